// Round 1
// 930.166 us; speedup vs baseline: 1.0574x; 1.0574x over previous
//
#include <hip/hip_runtime.h>

typedef unsigned short u16;
typedef __attribute__((ext_vector_type(8))) short short8;
typedef __attribute__((ext_vector_type(4))) float float4v;

__device__ __forceinline__ u16 f2b(float f) {
  union { float f; unsigned u; } v; v.f = f;
  unsigned r = v.u + 0x7fffu + ((v.u >> 16) & 1u);
  return (u16)(r >> 16);
}

#define AS1(p) ((const __attribute__((address_space(1))) void*)(p))
#define AS3(p) ((__attribute__((address_space(3))) void*)(p))
#define MFMA16(a, b, c) __builtin_amdgcn_mfma_f32_16x16x32_bf16(a, b, c, 0, 0, 0)

// ---------------- f32 -> bf16, contiguous ----------------
__global__ __launch_bounds__(256) void cvt_bf16_kernel(const float* __restrict__ in,
                                                       u16* __restrict__ out, long n) {
  long i = ((long)blockIdx.x * 256 + threadIdx.x) * 8;
  if (i + 8 > n) return;
  float4v a = *(const float4v*)(in + i);
  float4v b = *(const float4v*)(in + i + 4);
  short8 o;
  o[0] = (short)f2b(a[0]); o[1] = (short)f2b(a[1]);
  o[2] = (short)f2b(a[2]); o[3] = (short)f2b(a[3]);
  o[4] = (short)f2b(b[0]); o[5] = (short)f2b(b[1]);
  o[6] = (short)f2b(b[2]); o[7] = (short)f2b(b[3]);
  *(short8*)(out + i) = o;
}

// ------- transpose+convert: in[rows][cols] f32 -> out[cols][rows] bf16 -------
__global__ __launch_bounds__(256) void transpose_cvt_kernel(const float* __restrict__ in,
                                                            u16* __restrict__ out,
                                                            int rows, int cols) {
  __shared__ float tile[32][33];
  int bx = blockIdx.x * 32;
  int by = blockIdx.y * 32;
  int tx = threadIdx.x & 31, ty = threadIdx.x >> 5;
  for (int r = ty; r < 32; r += 8)
    tile[r][tx] = in[(long)(by + r) * cols + bx + tx];
  __syncthreads();
  for (int r = ty; r < 32; r += 8)
    out[(long)(bx + r) * rows + by + tx] = f2b(tile[tx][r]);
}

// =====================================================================
// 256x256 8-phase GEMM (m201 template, plain HIP):
//   C[M,N] = A[M,K] * B[N,K]^T + bias[N]
// 512 threads = 8 waves (2M x 4N); per-wave output 128x64; BK=64.
// LDS 128 KiB: 2 dbuf x 2 half-tiles(128x64 bf16) x {A,B}.
// Staging: global_load_lds width-16, LINEAR LDS dest + inverse-swizzled
// global source; ds_read side applies st_16x32 XOR (byte^=((byte>>9)&1)<<5,
// in elems: ^=((e>>8)&1)<<4). Same involution both sides (rule #21).
// Schedule per K-tile u (buf = u&1), 4 phases:
//   p0: ds_read B all(8)+A m0,m1(4); stage A-h0(u+1)->buf^1; lgkm(8); bar;
//       lgkm(0); prio1; 16 MFMA; prio0; bar
//   p1: ds_read A m2,m3; stage A-h1(u+1)->buf^1; bar; lgkm(0); 16 MFMA; bar
//   p2: ds_read A m4,m5; stage B-h0(u+2)->buf  ; bar; lgkm(0); 16 MFMA; bar
//   p3: ds_read A m6,m7; stage B-h1(u+2)->buf  ; bar; lgkm(0); 16 MFMA;
//       vmcnt(4); bar           <- counted: B(u+2) (4 loads) stays in flight
// B slots of buf are free after p0 (B frags held in regs for all 4 phases);
// A slots of buf^1 free since tile u-1's last barrier. Tail stages clamp the
// K-tile index: they rewrite never-again-read slots, keeping vmcnt uniform.
// Requires: M%256==0, N%256==0, K%128==0.
// =====================================================================
__global__ __launch_bounds__(512, 2) void gemm256_bt_bias(const u16* __restrict__ A,
                                                          const u16* __restrict__ B,
                                                          const float* __restrict__ bias,
                                                          void* __restrict__ Cout,
                                                          int M, int N, int K, int out_bf16) {
  __shared__ __align__(16) u16 As[2][2][8192];
  __shared__ __align__(16) u16 Bs[2][2][8192];

  const int t = threadIdx.x;
  const int lane = t & 63;
  const int w = t >> 6;
  const int wm = w >> 2;        // 0..1  (M half)
  const int wn = w & 3;         // 0..3  (N quarter)
  const int lm = lane & 15;
  const int lq = lane >> 4;

  // T1: bijective XCD-aware block swizzle (m204)
  const int nwg = gridDim.x * gridDim.y;
  const int orig = blockIdx.y * gridDim.x + blockIdx.x;
  const int qq = nwg >> 3, rr = nwg & 7;
  const int xcd = orig & 7, loc = orig >> 3;
  const int wgid = (xcd < rr ? xcd * (qq + 1) : rr * (qq + 1) + (xcd - rr) * qq) + loc;
  const int bx = wgid % gridDim.x;
  const int by = wgid / gridDim.x;

  const long row0 = (long)by * 256;
  const long col0 = (long)bx * 256;

  // Staging precompute: thread t writes physical elem offsets [t*8,+8) and
  // [4096+t*8,+8) of a half-tile; global source = logical = phys ^ swz.
  const int phys0 = t * 8;
  const int phys1 = 4096 + t * 8;
  const int log0 = phys0 ^ (((phys0 >> 8) & 1) << 4);
  const int log1 = phys1 ^ (((phys1 >> 8) & 1) << 4);
  const long r0s = log0 >> 6; const int c0s = log0 & 63;
  const long r1s = log1 >> 6; const int c1s = log1 & 63;

  const u16* Ag0 = A + (row0 + r0s) * K + c0s;
  const u16* Ag1 = A + (row0 + r1s) * K + c1s;
  const u16* Bg0 = B + (col0 + r0s) * K + c0s;
  const u16* Bg1 = B + (col0 + r1s) * K + c1s;
  const long hstride = 128L * (long)K;

  // Swizzled per-lane ds_read base (elems): row=lm (bit2 -> XOR bit4), col=lq*8
  const int sb = (lm * 64 + lq * 8) ^ (((lm >> 2) & 1) << 4);

  float4v acc[8][4] = {};
  const int NT = K >> 6;

  auto stA = [&](int buf, int h, int kt) {
    u16* d = &As[buf][h][0] + t * 8;
    const long ko = (long)kt * 64 + (long)h * hstride;
    __builtin_amdgcn_global_load_lds(AS1(Ag0 + ko), AS3(d), 16, 0, 0);
    __builtin_amdgcn_global_load_lds(AS1(Ag1 + ko), AS3(d + 4096), 16, 0, 0);
  };
  auto stB = [&](int buf, int h, int kt) {
    u16* d = &Bs[buf][h][0] + t * 8;
    const long ko = (long)kt * 64 + (long)h * hstride;
    __builtin_amdgcn_global_load_lds(AS1(Bg0 + ko), AS3(d), 16, 0, 0);
    __builtin_amdgcn_global_load_lds(AS1(Bg1 + ko), AS3(d + 4096), 16, 0, 0);
  };

  auto ktile = [&](int buf, int u) {
    asm volatile("" ::: "memory");  // no load hoisting across the tile boundary
    const u16* Ab = &As[buf][wm][0] + sb;
    const u16* Bb = &Bs[buf][wn >> 1][0] + (wn & 1) * 4096 + sb;
    const int kn  = (u + 1 < NT) ? u + 1 : NT - 1;
    const int kb2 = (u + 2 < NT) ? u + 2 : NT - 1;

    short8 bfr[4][2];
    // ---- phase 0: B frags (kept live all 4 phases) + A m0,m1 ----
#pragma unroll
    for (int n = 0; n < 4; n++) {
      bfr[n][0] = *(const short8*)(Bb + n * 1024);
      bfr[n][1] = *(const short8*)(Bb + n * 1024 + 32);
    }
    {
      short8 a00 = *(const short8*)(Ab + 0);
      short8 a01 = *(const short8*)(Ab + 32);
      short8 a10 = *(const short8*)(Ab + 1024);
      short8 a11 = *(const short8*)(Ab + 1024 + 32);
      stA(buf ^ 1, 0, kn);
      asm volatile("s_waitcnt lgkmcnt(8)" ::: "memory");
      __builtin_amdgcn_s_barrier();
      asm volatile("s_waitcnt lgkmcnt(0)" ::: "memory");
      __builtin_amdgcn_s_setprio(1);
#pragma unroll
      for (int n = 0; n < 4; n++) {
        acc[0][n] = MFMA16(a00, bfr[n][0], acc[0][n]);
        acc[0][n] = MFMA16(a01, bfr[n][1], acc[0][n]);
        acc[1][n] = MFMA16(a10, bfr[n][0], acc[1][n]);
        acc[1][n] = MFMA16(a11, bfr[n][1], acc[1][n]);
      }
      __builtin_amdgcn_s_setprio(0);
      __builtin_amdgcn_s_barrier();
    }
    // ---- phases 1..3: A m2..m7, one half-tile stage each ----
#pragma unroll
    for (int p = 1; p < 4; p++) {
      short8 a00 = *(const short8*)(Ab + (2 * p) * 1024);
      short8 a01 = *(const short8*)(Ab + (2 * p) * 1024 + 32);
      short8 a10 = *(const short8*)(Ab + (2 * p + 1) * 1024);
      short8 a11 = *(const short8*)(Ab + (2 * p + 1) * 1024 + 32);
      if (p == 1)      stA(buf ^ 1, 1, kn);
      else if (p == 2) stB(buf, 0, kb2);
      else             stB(buf, 1, kb2);
      __builtin_amdgcn_s_barrier();
      asm volatile("s_waitcnt lgkmcnt(0)" ::: "memory");
      __builtin_amdgcn_s_setprio(1);
#pragma unroll
      for (int n = 0; n < 4; n++) {
        acc[2 * p][n]     = MFMA16(a00, bfr[n][0], acc[2 * p][n]);
        acc[2 * p][n]     = MFMA16(a01, bfr[n][1], acc[2 * p][n]);
        acc[2 * p + 1][n] = MFMA16(a10, bfr[n][0], acc[2 * p + 1][n]);
        acc[2 * p + 1][n] = MFMA16(a11, bfr[n][1], acc[2 * p + 1][n]);
      }
      __builtin_amdgcn_s_setprio(0);
      if (p == 3) asm volatile("s_waitcnt vmcnt(4)" ::: "memory");
      __builtin_amdgcn_s_barrier();
    }
  };

  // Prologue: tile0 (A,B) + tile1 (B) staged; drain to 4 (tile0 landed, B(1) in flight)
  stA(0, 0, 0); stA(0, 1, 0); stB(0, 0, 0); stB(0, 1, 0);
  const int k1 = (NT > 1) ? 1 : 0;
  stB(1, 0, k1); stB(1, 1, k1);
  asm volatile("s_waitcnt vmcnt(4)" ::: "memory");
  __builtin_amdgcn_s_barrier();

  for (int u = 0; u < NT; u += 2) {
    ktile(0, u);
    ktile(1, u + 1);
  }

  // Epilogue: C/D layout col=lane&15, row=(lane>>4)*4+r
#pragma unroll
  for (int n = 0; n < 4; n++) {
    const long cg = col0 + wn * 64 + n * 16 + lm;
    const float bv = bias[cg];
#pragma unroll
    for (int m = 0; m < 8; m++) {
      const long rbase = row0 + wm * 128 + m * 16 + lq * 4;
#pragma unroll
      for (int r = 0; r < 4; r++) {
        const float v = acc[m][n][r] + bv;
        const long idx = (rbase + r) * N + cg;
        if (out_bf16) ((u16*)Cout)[idx] = f2b(v);
        else          ((float*)Cout)[idx] = v;
      }
    }
  }
}

// ------- Per-position head-mixing attention (matches the reference einsum!) -------
__global__ __launch_bounds__(256) void head_attn_kernel(const u16* __restrict__ qkv,
                                                        u16* __restrict__ ctx) {
  __shared__ __align__(16) u16 vt_s[4][128 * 16];  // per-wave V^T: vt[d][t]
  __shared__ __align__(16) u16 ws_s[4][16 * 32];   // per-wave W: ws[h][t], t padded to 32
  const int tid = threadIdx.x;
  const int lane = tid & 63;
  const int w = tid >> 6;
  const int lm = lane & 15, lq = lane >> 4;
  const int pos = blockIdx.x * 4 + w;             // 0..16383 = b*4096 + s
  const int b = pos >> 12, s = pos & 4095;
  const long rowb = (long)pos * 6144;

  u16* vt = vt_s[w];
  u16* wsp = ws_s[w];

  for (int i = lane; i < 16 * 32; i += 64) wsp[i] = 0;

  {
    int tt = lane >> 2, db = (lane & 3) * 32;
#pragma unroll
    for (int c = 0; c < 4; c++) {
      short8 vv = *(const short8*)(qkv + rowb + 4096 + tt * 128 + db + c * 8);
#pragma unroll
      for (int j = 0; j < 8; j++)
        vt[(db + c * 8 + j) * 16 + tt] = (u16)vv[j];
    }
  }
  __syncthreads();

  float4v st = {0.f, 0.f, 0.f, 0.f};
#pragma unroll
  for (int ks = 0; ks < 4; ks++) {
    short8 qa = *(const short8*)(qkv + rowb + lm * 128 + ks * 32 + lq * 8);
    short8 kb = *(const short8*)(qkv + rowb + 2048 + lm * 128 + ks * 32 + lq * 8);
    st = __builtin_amdgcn_mfma_f32_16x16x32_bf16(qa, kb, st, 0, 0, 0);
  }

  const float sc = 0.08838834764831845f * 1.4426950408889634f; // 1/sqrt(128)*log2(e)
#pragma unroll
  for (int r = 0; r < 4; r++) {
    float z = st[r] * sc;
    float m = z;
    m = fmaxf(m, __shfl_xor(m, 1));
    m = fmaxf(m, __shfl_xor(m, 2));
    m = fmaxf(m, __shfl_xor(m, 4));
    m = fmaxf(m, __shfl_xor(m, 8));
    float p = exp2f(z - m);
    float ss = p;
    ss += __shfl_xor(ss, 1);
    ss += __shfl_xor(ss, 2);
    ss += __shfl_xor(ss, 4);
    ss += __shfl_xor(ss, 8);
    wsp[(lq * 4 + r) * 32 + lm] = f2b(p / ss);
  }
  __syncthreads();

  short8 wa = *(const short8*)(wsp + lm * 32 + lq * 8);
#pragma unroll
  for (int dt = 0; dt < 8; dt++) {
    short8 vb = *(const short8*)(vt + (dt * 16 + lm) * 16 + (lq & 1) * 8);
    float4v o = {0.f, 0.f, 0.f, 0.f};
    o = __builtin_amdgcn_mfma_f32_16x16x32_bf16(wa, vb, o, 0, 0, 0);
#pragma unroll
    for (int r = 0; r < 4; r++) {
      int h = lq * 4 + r;
      ctx[(((long)(b * 16 + h) * 4096 + s) * 128) + dt * 16 + lm] = f2b(o[r]);
    }
  }
}

extern "C" void kernel_launch(void* const* d_in, const int* in_sizes, int n_in,
                              void* d_out, int out_size, void* d_ws, size_t ws_size,
                              hipStream_t stream) {
  const float* x     = (const float*)d_in[0];  // [4,4096,2048]
  const float* Wqkv  = (const float*)d_in[1];  // [2048,6144]
  const float* bqkv  = (const float*)d_in[2];  // [6144]
  const float* Wproj = (const float*)d_in[3];  // [2048,2048]
  const float* bproj = (const float*)d_in[4];  // [2048]
  float* out = (float*)d_out;                  // [4,4096,2048] f32

  // workspace layout (bf16 elements)
  u16* xb     = (u16*)d_ws;                    // 33,554,432
  u16* WqkvT  = xb + 33554432L;                // 12,582,912  (6144 x 2048)
  u16* WprojT = WqkvT + 12582912L;             //  4,194,304  (2048 x 2048)
  u16* qkvb   = WprojT + 4194304L;             // 100,663,296 (16384 x 6144)
  u16* ctxb   = qkvb + 100663296L;             // 33,554,432  (B,H,S,D) flat

  cvt_bf16_kernel<<<33554432L / 2048, 256, 0, stream>>>(x, xb, 33554432L);
  transpose_cvt_kernel<<<dim3(6144 / 32, 2048 / 32), 256, 0, stream>>>(Wqkv, WqkvT, 2048, 6144);
  transpose_cvt_kernel<<<dim3(2048 / 32, 2048 / 32), 256, 0, stream>>>(Wproj, WprojT, 2048, 2048);

  // qkv = x @ Wqkv + bqkv  (bf16 out)
  gemm256_bt_bias<<<dim3(6144 / 256, 16384 / 256), 512, 0, stream>>>(
      xb, WqkvT, bqkv, qkvb, 16384, 6144, 2048, 1);

  // per-position head-mixing attention -> context in (B,H,S,D) order (bf16)
  head_attn_kernel<<<4096, 256, 0, stream>>>(qkvb, ctxb);

  // out = ctx_view @ Wproj + bproj (f32 out)
  gemm256_bt_bias<<<dim3(2048 / 256, 16384 / 256), 512, 0, stream>>>(
      ctxb, WprojT, bproj, out, 16384, 2048, 2048, 0);
}

// Round 2
// 900.197 us; speedup vs baseline: 1.0926x; 1.0333x over previous
//
#include <hip/hip_runtime.h>

typedef unsigned short u16;
typedef __attribute__((ext_vector_type(8))) short short8;
typedef __attribute__((ext_vector_type(4))) float float4v;

__device__ __forceinline__ u16 f2b(float f) {
  union { float f; unsigned u; } v; v.f = f;
  unsigned r = v.u + 0x7fffu + ((v.u >> 16) & 1u);
  return (u16)(r >> 16);
}

#define AS1(p) ((const __attribute__((address_space(1))) void*)(p))
#define AS3(p) ((__attribute__((address_space(3))) void*)(p))
#define MFMA16(a, b, c) __builtin_amdgcn_mfma_f32_16x16x32_bf16(a, b, c, 0, 0, 0)

// ---------------- f32 -> bf16, contiguous ----------------
__global__ __launch_bounds__(256) void cvt_bf16_kernel(const float* __restrict__ in,
                                                       u16* __restrict__ out, long n) {
  long i = ((long)blockIdx.x * 256 + threadIdx.x) * 8;
  if (i + 8 > n) return;
  float4v a = *(const float4v*)(in + i);
  float4v b = *(const float4v*)(in + i + 4);
  short8 o;
  o[0] = (short)f2b(a[0]); o[1] = (short)f2b(a[1]);
  o[2] = (short)f2b(a[2]); o[3] = (short)f2b(a[3]);
  o[4] = (short)f2b(b[0]); o[5] = (short)f2b(b[1]);
  o[6] = (short)f2b(b[2]); o[7] = (short)f2b(b[3]);
  *(short8*)(out + i) = o;
}

// ------- transpose+convert: in[rows][cols] f32 -> out[cols][rows] bf16 -------
__global__ __launch_bounds__(256) void transpose_cvt_kernel(const float* __restrict__ in,
                                                            u16* __restrict__ out,
                                                            int rows, int cols) {
  __shared__ float tile[32][33];
  int bx = blockIdx.x * 32;
  int by = blockIdx.y * 32;
  int tx = threadIdx.x & 31, ty = threadIdx.x >> 5;
  for (int r = ty; r < 32; r += 8)
    tile[r][tx] = in[(long)(by + r) * cols + bx + tx];
  __syncthreads();
  for (int r = ty; r < 32; r += 8)
    out[(long)(bx + r) * rows + by + tx] = f2b(tile[tx][r]);
}

// =====================================================================
// 256x256 8-phase GEMM:  C[M,N] = A[M,K] * B[N,K]^T + bias[N]
// 512 threads = 8 waves (2M x 4N); per-wave output 128x64; BK=64.
// LDS 128 KiB: 2 dbuf x 2 half-tiles(128x64 bf16) x {A,B}.
//
// T2 swizzle (round-2 fix): 3-bit XOR, col ^= (row&7)<<3 (elems), i.e.
// byte ^= (row&7)<<4 — the m214-verified fix for ds_read_b128 of a
// row-major 128B-stride tile. Quad-bank = lq ^ (lm&7): 16-way -> even
// 8-way (floor). Both sides: staging loads logical = phys ^ swz(row)
// (linear LDS dest per global_load_lds), reads apply the same involution.
// NOTE: swizzle touches col bit 5, so the k-slice "+32" becomes XOR 32
// (two base pointers, lo/hi) — (a^32) != (a+32) when lm&4.
//
// Schedule per K-tile u (buf = u&1), 4 phases (m201 cadence):
//   p0: ds_read B all(8)+A m0,m1(4); stage A-h0(u+1)->buf^1; lgkm(8); bar;
//       lgkm(0); prio1; 16 MFMA; prio0; bar
//   p1: ds_read A m2,m3; stage A-h1(u+1)->buf^1; bar; lgkm(0); 16 MFMA; bar
//   p2: ds_read A m4,m5; stage B-h0(u+2)->buf  ; bar; lgkm(0); 16 MFMA; bar
//   p3: ds_read A m6,m7; stage B-h1(u+2)->buf  ; bar; lgkm(0); 16 MFMA;
//       vmcnt(4); bar           <- counted: B(u+2) (4 loads) stays in flight
// Tail stages clamp the K-tile index (rewrite never-again-read slots,
// vmcnt count stays uniform). Requires: M%256==0, N%256==0, K%128==0.
// =====================================================================
__global__ __launch_bounds__(512, 2) void gemm256_bt_bias(const u16* __restrict__ A,
                                                          const u16* __restrict__ B,
                                                          const float* __restrict__ bias,
                                                          void* __restrict__ Cout,
                                                          int M, int N, int K, int out_bf16) {
  __shared__ __align__(16) u16 As[2][2][8192];
  __shared__ __align__(16) u16 Bs[2][2][8192];

  const int t = threadIdx.x;
  const int lane = t & 63;
  const int w = t >> 6;
  const int wm = w >> 2;        // 0..1  (M half)
  const int wn = w & 3;         // 0..3  (N quarter)
  const int lm = lane & 15;
  const int lq = lane >> 4;

  // T1: bijective XCD-aware block swizzle (m204)
  const int nwg = gridDim.x * gridDim.y;
  const int orig = blockIdx.y * gridDim.x + blockIdx.x;
  const int qq = nwg >> 3, rr = nwg & 7;
  const int xcd = orig & 7, loc = orig >> 3;
  const int wgid = (xcd < rr ? xcd * (qq + 1) : rr * (qq + 1) + (xcd - rr) * qq) + loc;
  const int bx = wgid % gridDim.x;
  const int by = wgid / gridDim.x;

  const long row0 = (long)by * 256;
  const long col0 = (long)bx * 256;

  // Staging: thread t writes physical elem chunks [t*8,+8) and [4096+t*8,+8)
  // of a half-tile (linear dest); global source = logical = phys ^ swz(row).
  // swz(e) = ((row&7)<<3) on col bits [5:3]; row = e>>6 (row of h1 = row+64,
  // same &7, so log1 = log0 + 4096).
  const int phys0 = t * 8;
  const int log0 = phys0 ^ (((phys0 >> 6) & 7) << 3);
  const long r0s = log0 >> 6; const int c0s = log0 & 63;
  const long r1s = r0s + 64;  const int c1s = c0s;

  const u16* Ag0 = A + (row0 + r0s) * K + c0s;
  const u16* Ag1 = A + (row0 + r1s) * K + c1s;
  const u16* Bg0 = B + (col0 + r0s) * K + c0s;
  const u16* Bg1 = B + (col0 + r1s) * K + c1s;
  const long hstride = 128L * (long)K;

  // Swizzled per-lane ds_read bases (elems): row=lm, col=lq*8 (slice lo)
  // and col=lq*8+32 (slice hi); col ^= (lm&7)<<3. m*1024 offsets (bit 10+)
  // don't interact with the swizzled bits [5:3].
  const int sb  = lm * 64 + ((lq * 8) ^ ((lm & 7) << 3));
  const int sbx = sb ^ 32;

  float4v acc[8][4] = {};
  const int NT = K >> 6;

  auto stA = [&](int buf, int h, int kt) {
    u16* d = &As[buf][h][0] + t * 8;
    const long ko = (long)kt * 64 + (long)h * hstride;
    __builtin_amdgcn_global_load_lds(AS1(Ag0 + ko), AS3(d), 16, 0, 0);
    __builtin_amdgcn_global_load_lds(AS1(Ag1 + ko), AS3(d + 4096), 16, 0, 0);
  };
  auto stB = [&](int buf, int h, int kt) {
    u16* d = &Bs[buf][h][0] + t * 8;
    const long ko = (long)kt * 64 + (long)h * hstride;
    __builtin_amdgcn_global_load_lds(AS1(Bg0 + ko), AS3(d), 16, 0, 0);
    __builtin_amdgcn_global_load_lds(AS1(Bg1 + ko), AS3(d + 4096), 16, 0, 0);
  };

  auto ktile = [&](int buf, int u) {
    asm volatile("" ::: "memory");  // no load hoisting across the tile boundary
    const u16* Abl = &As[buf][wm][0] + sb;
    const u16* Abh = &As[buf][wm][0] + sbx;
    const u16* Bbl = &Bs[buf][wn >> 1][0] + (wn & 1) * 4096 + sb;
    const u16* Bbh = &Bs[buf][wn >> 1][0] + (wn & 1) * 4096 + sbx;
    const int kn  = (u + 1 < NT) ? u + 1 : NT - 1;
    const int kb2 = (u + 2 < NT) ? u + 2 : NT - 1;

    short8 bfr[4][2];
    // ---- phase 0: B frags (kept live all 4 phases) + A m0,m1 ----
#pragma unroll
    for (int n = 0; n < 4; n++) {
      bfr[n][0] = *(const short8*)(Bbl + n * 1024);
      bfr[n][1] = *(const short8*)(Bbh + n * 1024);
    }
    {
      short8 a00 = *(const short8*)(Abl + 0);
      short8 a01 = *(const short8*)(Abh + 0);
      short8 a10 = *(const short8*)(Abl + 1024);
      short8 a11 = *(const short8*)(Abh + 1024);
      stA(buf ^ 1, 0, kn);
      asm volatile("s_waitcnt lgkmcnt(8)" ::: "memory");
      __builtin_amdgcn_s_barrier();
      asm volatile("s_waitcnt lgkmcnt(0)" ::: "memory");
      __builtin_amdgcn_s_setprio(1);
#pragma unroll
      for (int n = 0; n < 4; n++) {
        acc[0][n] = MFMA16(a00, bfr[n][0], acc[0][n]);
        acc[0][n] = MFMA16(a01, bfr[n][1], acc[0][n]);
        acc[1][n] = MFMA16(a10, bfr[n][0], acc[1][n]);
        acc[1][n] = MFMA16(a11, bfr[n][1], acc[1][n]);
      }
      __builtin_amdgcn_s_setprio(0);
      __builtin_amdgcn_s_barrier();
    }
    // ---- phases 1..3: A m2..m7, one half-tile stage each ----
#pragma unroll
    for (int p = 1; p < 4; p++) {
      short8 a00 = *(const short8*)(Abl + (2 * p) * 1024);
      short8 a01 = *(const short8*)(Abh + (2 * p) * 1024);
      short8 a10 = *(const short8*)(Abl + (2 * p + 1) * 1024);
      short8 a11 = *(const short8*)(Abh + (2 * p + 1) * 1024);
      if (p == 1)      stA(buf ^ 1, 1, kn);
      else if (p == 2) stB(buf, 0, kb2);
      else             stB(buf, 1, kb2);
      __builtin_amdgcn_s_barrier();
      asm volatile("s_waitcnt lgkmcnt(0)" ::: "memory");
      __builtin_amdgcn_s_setprio(1);
#pragma unroll
      for (int n = 0; n < 4; n++) {
        acc[2 * p][n]     = MFMA16(a00, bfr[n][0], acc[2 * p][n]);
        acc[2 * p][n]     = MFMA16(a01, bfr[n][1], acc[2 * p][n]);
        acc[2 * p + 1][n] = MFMA16(a10, bfr[n][0], acc[2 * p + 1][n]);
        acc[2 * p + 1][n] = MFMA16(a11, bfr[n][1], acc[2 * p + 1][n]);
      }
      __builtin_amdgcn_s_setprio(0);
      if (p == 3) asm volatile("s_waitcnt vmcnt(4)" ::: "memory");
      __builtin_amdgcn_s_barrier();
    }
  };

  // Prologue: tile0 (A,B) + tile1 (B) staged; drain to 4 (tile0 landed, B(1) in flight)
  stA(0, 0, 0); stA(0, 1, 0); stB(0, 0, 0); stB(0, 1, 0);
  const int k1 = (NT > 1) ? 1 : 0;
  stB(1, 0, k1); stB(1, 1, k1);
  asm volatile("s_waitcnt vmcnt(4)" ::: "memory");
  __builtin_amdgcn_s_barrier();

  for (int u = 0; u < NT; u += 2) {
    ktile(0, u);
    ktile(1, u + 1);
  }

  // Epilogue: C/D layout col=lane&15, row=(lane>>4)*4+r
#pragma unroll
  for (int n = 0; n < 4; n++) {
    const long cg = col0 + wn * 64 + n * 16 + lm;
    const float bv = bias[cg];
#pragma unroll
    for (int m = 0; m < 8; m++) {
      const long rbase = row0 + wm * 128 + m * 16 + lq * 4;
#pragma unroll
      for (int r = 0; r < 4; r++) {
        const float v = acc[m][n][r] + bv;
        const long idx = (rbase + r) * N + cg;
        if (out_bf16) ((u16*)Cout)[idx] = f2b(v);
        else          ((float*)Cout)[idx] = v;
      }
    }
  }
}

// ------- Per-position head-mixing attention (matches the reference einsum!) -------
__global__ __launch_bounds__(256) void head_attn_kernel(const u16* __restrict__ qkv,
                                                        u16* __restrict__ ctx) {
  __shared__ __align__(16) u16 vt_s[4][128 * 16];  // per-wave V^T: vt[d][t]
  __shared__ __align__(16) u16 ws_s[4][16 * 32];   // per-wave W: ws[h][t], t padded to 32
  const int tid = threadIdx.x;
  const int lane = tid & 63;
  const int w = tid >> 6;
  const int lm = lane & 15, lq = lane >> 4;
  const int pos = blockIdx.x * 4 + w;             // 0..16383 = b*4096 + s
  const int b = pos >> 12, s = pos & 4095;
  const long rowb = (long)pos * 6144;

  u16* vt = vt_s[w];
  u16* wsp = ws_s[w];

  for (int i = lane; i < 16 * 32; i += 64) wsp[i] = 0;

  {
    int tt = lane >> 2, db = (lane & 3) * 32;
#pragma unroll
    for (int c = 0; c < 4; c++) {
      short8 vv = *(const short8*)(qkv + rowb + 4096 + tt * 128 + db + c * 8);
#pragma unroll
      for (int j = 0; j < 8; j++)
        vt[(db + c * 8 + j) * 16 + tt] = (u16)vv[j];
    }
  }
  __syncthreads();

  float4v st = {0.f, 0.f, 0.f, 0.f};
#pragma unroll
  for (int ks = 0; ks < 4; ks++) {
    short8 qa = *(const short8*)(qkv + rowb + lm * 128 + ks * 32 + lq * 8);
    short8 kb = *(const short8*)(qkv + rowb + 2048 + lm * 128 + ks * 32 + lq * 8);
    st = __builtin_amdgcn_mfma_f32_16x16x32_bf16(qa, kb, st, 0, 0, 0);
  }

  const float sc = 0.08838834764831845f * 1.4426950408889634f; // 1/sqrt(128)*log2(e)
#pragma unroll
  for (int r = 0; r < 4; r++) {
    float z = st[r] * sc;
    float m = z;
    m = fmaxf(m, __shfl_xor(m, 1));
    m = fmaxf(m, __shfl_xor(m, 2));
    m = fmaxf(m, __shfl_xor(m, 4));
    m = fmaxf(m, __shfl_xor(m, 8));
    float p = exp2f(z - m);
    float ss = p;
    ss += __shfl_xor(ss, 1);
    ss += __shfl_xor(ss, 2);
    ss += __shfl_xor(ss, 4);
    ss += __shfl_xor(ss, 8);
    wsp[(lq * 4 + r) * 32 + lm] = f2b(p / ss);
  }
  __syncthreads();

  short8 wa = *(const short8*)(wsp + lm * 32 + lq * 8);
#pragma unroll
  for (int dt = 0; dt < 8; dt++) {
    short8 vb = *(const short8*)(vt + (dt * 16 + lm) * 16 + (lq & 1) * 8);
    float4v o = {0.f, 0.f, 0.f, 0.f};
    o = __builtin_amdgcn_mfma_f32_16x16x32_bf16(wa, vb, o, 0, 0, 0);
#pragma unroll
    for (int r = 0; r < 4; r++) {
      int h = lq * 4 + r;
      ctx[(((long)(b * 16 + h) * 4096 + s) * 128) + dt * 16 + lm] = f2b(o[r]);
    }
  }
}

extern "C" void kernel_launch(void* const* d_in, const int* in_sizes, int n_in,
                              void* d_out, int out_size, void* d_ws, size_t ws_size,
                              hipStream_t stream) {
  const float* x     = (const float*)d_in[0];  // [4,4096,2048]
  const float* Wqkv  = (const float*)d_in[1];  // [2048,6144]
  const float* bqkv  = (const float*)d_in[2];  // [6144]
  const float* Wproj = (const float*)d_in[3];  // [2048,2048]
  const float* bproj = (const float*)d_in[4];  // [2048]
  float* out = (float*)d_out;                  // [4,4096,2048] f32

  // workspace layout (bf16 elements)
  u16* xb     = (u16*)d_ws;                    // 33,554,432
  u16* WqkvT  = xb + 33554432L;                // 12,582,912  (6144 x 2048)
  u16* WprojT = WqkvT + 12582912L;             //  4,194,304  (2048 x 2048)
  u16* qkvb   = WprojT + 4194304L;             // 100,663,296 (16384 x 6144)
  u16* ctxb   = qkvb + 100663296L;             // 33,554,432  (B,H,S,D) flat

  cvt_bf16_kernel<<<33554432L / 2048, 256, 0, stream>>>(x, xb, 33554432L);
  transpose_cvt_kernel<<<dim3(6144 / 32, 2048 / 32), 256, 0, stream>>>(Wqkv, WqkvT, 2048, 6144);
  transpose_cvt_kernel<<<dim3(2048 / 32, 2048 / 32), 256, 0, stream>>>(Wproj, WprojT, 2048, 2048);

  // qkv = x @ Wqkv + bqkv  (bf16 out)
  gemm256_bt_bias<<<dim3(6144 / 256, 16384 / 256), 512, 0, stream>>>(
      xb, WqkvT, bqkv, qkvb, 16384, 6144, 2048, 1);

  // per-position head-mixing attention -> context in (B,H,S,D) order (bf16)
  head_attn_kernel<<<4096, 256, 0, stream>>>(qkvb, ctxb);

  // out = ctx_view @ Wproj + bproj (f32 out)
  gemm256_bt_bias<<<dim3(2048 / 256, 16384 / 256), 512, 0, stream>>>(
      ctxb, WprojT, bproj, out, 16384, 2048, 2048, 0);
}